// Round 5
// baseline (232.654 us; speedup 1.0000x reference)
//
#include <hip/hip_runtime.h>

// PermuteWeightSharing: out[row, s*16+k] = x[row, ppos[s]*16+k] - x[row, pneg[s]*16+k]
// row = (b,o,i) flattened, 256 floats per row = 16 slots x 16 floats = 64 float4.
//
// v6 = v5 + nontemporal stores (single-variable A/B vs round 4).
// Evidence: during-kernel TCC traffic is exactly our logical bytes at only
// 2.4 TB/s, while harness fills stream writes at 6.7 TB/s and leave L3's x
// contents intact (FETCH=66MB after 2x536MB fills => fills use no-allocate
// streaming stores). Theory: plain stores pay L2/L3 write-allocate; NT
// stores take the fill's streaming path. Round 1's NT test was confounded
// by the grid-stride loop's vmcnt serialization (loads queued behind prior
// stores in the in-order vmcnt retire); in straight-line one-shot code
// stores follow all loads and never block a load wait.
// Per position: 1 sequential 16B load, 8 ds_bpermute, 1 sequential NT store.

#define NSLOTS 16

typedef float fvec4 __attribute__((ext_vector_type(4)));

__device__ inline fvec4 lane_gather(fvec4 a, int byte_addr)
{
    fvec4 r;
    r.x = __int_as_float(__builtin_amdgcn_ds_bpermute(byte_addr, __float_as_int(a.x)));
    r.y = __int_as_float(__builtin_amdgcn_ds_bpermute(byte_addr, __float_as_int(a.y)));
    r.z = __int_as_float(__builtin_amdgcn_ds_bpermute(byte_addr, __float_as_int(a.z)));
    r.w = __int_as_float(__builtin_amdgcn_ds_bpermute(byte_addr, __float_as_int(a.w)));
    return r;
}

__global__ __launch_bounds__(256, 8) void permute_ws_kernel(
    const fvec4* __restrict__ x,
    const float* __restrict__ Ppos,
    const float* __restrict__ Pneg,
    fvec4* __restrict__ out,
    int total_v4)
{
    __shared__ int spos[NSLOTS];
    __shared__ int sneg[NSLOTS];

    const int t = threadIdx.x;
    if (t < NSLOTS) {
        int ip = 0, in_ = 0;
        #pragma unroll
        for (int j = 0; j < NSLOTS; ++j) {
            if (Ppos[t * NSLOTS + j] > 0.5f) ip = j;
            if (Pneg[t * NSLOTS + j] > 0.5f) in_ = j;
        }
        spos[t] = ip;
        sneg[t] = in_;
    }
    __syncthreads();

    // Lane l of each wave holds float4 l of one row (sequential load).
    // Output lane v needs input lane pv = spos[v>>2]*4 + (v&3) of the SAME
    // wave (one wave-position == one 64-float4 row). ds_bpermute byte addr
    // = src_lane * 4.
    const int v  = t & 63;
    const int bp = ((spos[v >> 2] << 2) | (v & 3)) << 2;
    const int bn = ((sneg[v >> 2] << 2) | (v & 3)) << 2;

    // Block covers 16 rows = 1024 float4; thread t handles 4 rows at the
    // same within-row position: i0, i0+256, i0+512, i0+768.
    const int i0 = blockIdx.x * 1024 + t;

    if (i0 + 768 < total_v4) {
        // 4 sequential loads in flight, then shuffle + NT-store each.
        const fvec4 a0 = x[i0 +   0];
        const fvec4 a1 = x[i0 + 256];
        const fvec4 a2 = x[i0 + 512];
        const fvec4 a3 = x[i0 + 768];
        const fvec4 r0 = lane_gather(a0, bp) - lane_gather(a0, bn);
        __builtin_nontemporal_store(r0, &out[i0 +   0]);
        const fvec4 r1 = lane_gather(a1, bp) - lane_gather(a1, bn);
        __builtin_nontemporal_store(r1, &out[i0 + 256]);
        const fvec4 r2 = lane_gather(a2, bp) - lane_gather(a2, bn);
        __builtin_nontemporal_store(r2, &out[i0 + 512]);
        const fvec4 r3 = lane_gather(a3, bp) - lane_gather(a3, bn);
        __builtin_nontemporal_store(r3, &out[i0 + 768]);
    } else {
        // Tail: total_v4 is a multiple of 64, so each wave-position's guard
        // is wave-uniform (bpermute sees all lanes active or none).
        #pragma unroll
        for (int j = 0; j < 4; ++j) {
            const int i = i0 + 256 * j;
            if (i < total_v4) {
                const fvec4 a = x[i];
                const fvec4 r = lane_gather(a, bp) - lane_gather(a, bn);
                __builtin_nontemporal_store(r, &out[i]);
            }
        }
    }
}

extern "C" void kernel_launch(void* const* d_in, const int* in_sizes, int n_in,
                              void* d_out, int out_size, void* d_ws, size_t ws_size,
                              hipStream_t stream)
{
    const fvec4* x    = (const fvec4*)d_in[0];
    const float* Ppos = (const float*)d_in[1];
    const float* Pneg = (const float*)d_in[2];
    fvec4*       out  = (fvec4*)d_out;

    const int total_v4 = out_size / 4;   // 33,554,432 / 4 = 8,388,608

    const int block = 256;
    // Each block covers 1024 float4 (16 rows, 4 per thread): 8192 blocks.
    const int grid = (total_v4 + 1023) / 1024;

    permute_ws_kernel<<<grid, block, 0, stream>>>(x, Ppos, Pneg, out, total_v4);
}

// Round 6
// 228.026 us; speedup vs baseline: 1.0203x; 1.0203x over previous
//
#include <hip/hip_runtime.h>

// PermuteWeightSharing: out[row, s*16+k] = x[row, ppos[s]*16+k] - x[row, pneg[s]*16+k]
// row = (b,o,i) flattened, 256 floats per row = 16 slots x 16 floats = 64 float4.
//
// v7: v0 geometry (best known, ~70 us kernel) + 2 row-positions per thread.
// Ledger: v0~70 (scattered, MLP=1, 32768 blk), loop~85, MLP4@8192blk~77,
// bpermute~76, NT~79. All variants pinned at ~64KB in-flight per CU (MLP
// gains canceled by VGPR/occupancy losses) => latency-bound at ~2.6 TB/s.
// This probe doubles in-flight bytes (4 loads x 16B x 2048 thr/CU = 128KB/CU)
// while keeping only 4 live fvec4 (~40 VGPR, full 32 waves/CU) and v0's
// high-turnover block structure. Scattered dual gather (fastest measured),
// plain stores, straight-line (no loop-carried vmcnt chain).

#define NSLOTS 16

typedef float fvec4 __attribute__((ext_vector_type(4)));

__global__ __launch_bounds__(256, 8) void permute_ws_kernel(
    const fvec4* __restrict__ x,
    const float* __restrict__ Ppos,
    const float* __restrict__ Pneg,
    fvec4* __restrict__ out,
    int total_v4)
{
    __shared__ int soff_p[NSLOTS];   // ppos[s] * 4  (float4 units)
    __shared__ int soff_n[NSLOTS];

    const int t = threadIdx.x;
    if (t < NSLOTS) {
        int ip = 0, in_ = 0;
        #pragma unroll
        for (int j = 0; j < NSLOTS; ++j) {
            if (Ppos[t * NSLOTS + j] > 0.5f) ip = j;
            if (Pneg[t * NSLOTS + j] > 0.5f) in_ = j;
        }
        soff_p[t] = ip << 2;
        soff_n[t] = in_ << 2;
    }
    __syncthreads();

    // Within-row geometry (block offset 512 is a multiple of 64, so v is
    // the same for both positions).
    const int v    = t & 63;
    const int slot = v >> 2;
    const int k4   = v & 3;
    // x index = row_base + soff + k4 = i + (soff + k4 - v)
    const int dp = soff_p[slot] + k4 - v;
    const int dn = soff_n[slot] + k4 - v;

    // Block covers 512 float4 = 8 rows; thread t handles positions i0, i0+256.
    const int i0 = blockIdx.x * 512 + t;
    const int i1 = i0 + 256;

    if (i1 < total_v4) {
        // 4 independent gathers in flight before any wait.
        const fvec4 a0 = x[i0 + dp];
        const fvec4 b0 = x[i0 + dn];
        const fvec4 a1 = x[i1 + dp];
        const fvec4 b1 = x[i1 + dn];
        out[i0] = a0 - b0;
        out[i1] = a1 - b1;
    } else if (i0 < total_v4) {
        const fvec4 a0 = x[i0 + dp];
        const fvec4 b0 = x[i0 + dn];
        out[i0] = a0 - b0;
    }
}

extern "C" void kernel_launch(void* const* d_in, const int* in_sizes, int n_in,
                              void* d_out, int out_size, void* d_ws, size_t ws_size,
                              hipStream_t stream)
{
    const fvec4* x    = (const fvec4*)d_in[0];
    const float* Ppos = (const float*)d_in[1];
    const float* Pneg = (const float*)d_in[2];
    fvec4*       out  = (fvec4*)d_out;

    const int total_v4 = out_size / 4;   // 33,554,432 / 4 = 8,388,608

    const int block = 256;
    // Each block covers 512 float4 (8 rows, 2 per thread): 16384 blocks.
    const int grid = (total_v4 + 511) / 512;

    permute_ws_kernel<<<grid, block, 0, stream>>>(x, Ppos, Pneg, out, total_v4);
}